// Round 10
// baseline (226.605 us; speedup 1.0000x reference)
//
#include <hip/hip_runtime.h>
#include <math.h>

#define S_LEN    16
#define NTOK     64     // tokens, m = s*4 + b
#define DMODEL   512
#define XB_COLS  2176   // x part (2048) + B part (128); z and C parts are dead code
#define ZX_COLS  2240   // XB_COLS + 64 dt columns
#define NCLASS   2513
#define FEATDIM  4096

// ---------------- k_xt: X (B,S,D) -> k-panel layout Xtp[(k/4)][m][4] -------------
__global__ void k_xt(const float* __restrict__ X, float* __restrict__ Xtp) {
    const int i = blockIdx.x * 256 + threadIdx.x;   // 8192 = 128 quads * 64 tokens
    const int kq = i >> 6, m = i & 63;
    const int row = (m & 3) * 16 + (m >> 2);        // inputs row b*16+s for token m=s*4+b
    const float4 v = *reinterpret_cast<const float4*>(X + (size_t)row * DMODEL + kq * 4);
    *reinterpret_cast<float4*>(Xtp + (size_t)i * 4) = v;
}

#define FMA4(A, W, F) \
    A += W.x * F.x + W.y * F.y + W.z * F.z + W.w * F.w

// ---------------- k_fpart: in_proj partials, LDS-staged weights ------------------
// grid (35, 8) x 256 thr (4 waves). Block: 64 cols x 64-k chunk. Wave: 16 cols as
// 8 class-pairs; lane (m2,h) handles tokens {m2, m2+32} for pair-slot h.
// Each ds_read_b128 (2-addr broadcast, free) feeds 8 FMAs.
__global__ __launch_bounds__(256, 3) void k_fpart(const float* __restrict__ Xtp,
                                                  const float* __restrict__ W,
                                                  float* __restrict__ partF) {
    const int tid = threadIdx.x;
    const int m2  = tid & 31;
    const int h   = (tid >> 5) & 1;
    const int wv  = tid >> 6;
    const int kf  = blockIdx.y;                  // 64-k chunk
    const int jb  = blockIdx.x * 64;             // 2240 = 35*64 exact
    const int e0  = (jb < XB_COLS) ? (2048 + jb) : (2176 + jb);  // contiguous rows

    __shared__ float Wl[64][64];

    // stage: 64 rows x 64 k, coalesced float4
    {
        const int r0 = tid >> 4, ks = tid & 15;
        const int kbase = kf * 64;
#pragma unroll
        for (int j = 0; j < 4; ++j) {
            const int row = r0 + j * 16;
            *reinterpret_cast<float4*>(&Wl[row][ks * 4]) =
                *reinterpret_cast<const float4*>(W + (size_t)(e0 + row) * DMODEL + kbase + ks * 4);
        }
    }
    __syncthreads();

    const float4* fp4 = reinterpret_cast<const float4*>(Xtp);
    float accA[8] = {0,0,0,0,0,0,0,0}, accB[8] = {0,0,0,0,0,0,0,0};

#pragma unroll
    for (int hs = 0; hs < 2; ++hs) {            // 32-k half-subtiles
        const int kq0 = kf * 16 + hs * 8;
        float4 fa[8], fb[8];
#pragma unroll
        for (int q = 0; q < 8; ++q) {
            fa[q] = fp4[(size_t)(kq0 + q) * 64 + m2];
            fb[q] = fp4[(size_t)(kq0 + q) * 64 + m2 + 32];
        }
#pragma unroll
        for (int p = 0; p < 8; ++p) {
            const int wrow = (wv << 4) + (p << 1) + h;
#pragma unroll
            for (int q = 0; q < 8; ++q) {
                const float4 wq = *reinterpret_cast<const float4*>(&Wl[wrow][(hs * 8 + q) * 4]);
                FMA4(accA[p], wq, fa[q]);
                FMA4(accB[p], wq, fb[q]);
            }
        }
    }

#pragma unroll
    for (int p = 0; p < 8; ++p) {
        const int j = jb + (wv << 4) + (p << 1) + h;
        partF[((size_t)kf * ZX_COLS + j) * 64 + m2]      = accA[p];
        partF[((size_t)kf * ZX_COLS + j) * 64 + m2 + 32] = accB[p];
    }
}

// ---------------- k_fepi: reduce partials + conv/silu + dt/dA ---------------------
__global__ __launch_bounds__(256) void k_fepi(const float* __restrict__ partF, int KF,
                                              const float* __restrict__ conv_w,
                                              const float* __restrict__ conv_b,
                                              const float* __restrict__ dt_bias,
                                              const float* __restrict__ A_log,
                                              float* __restrict__ u,
                                              float* __restrict__ aArr,
                                              float* __restrict__ dArr) {
    const int lane = threadIdx.x & 63;                 // token m
    const int j    = blockIdx.x * 4 + (threadIdx.x >> 6);
    float acc = 0.f;
    for (int kf = 0; kf < KF; ++kf)
        acc += partF[((size_t)kf * ZX_COLS + j) * 64 + lane];

    if (j < XB_COLS) {
        const float4 cwv = *reinterpret_cast<const float4*>(conv_w + j * 4);
        const float cb = conv_b[j];
        float wk[4];
        wk[0] = cwv.w;                  // cw[:,0] = conv_w[:,3]
        wk[1] = wk[0] + cwv.z;
        wk[2] = wk[1] + cwv.y;
        wk[3] = wk[2] + cwv.x;
#pragma unroll
        for (int k = 0; k < 4; ++k) {
            const float v = acc * wk[k] + cb;
            u[((size_t)k * NTOK + lane) * XB_COLS + j] = v / (1.f + expf(-v));
        }
    } else {
        const int h = j - XB_COLS;
        const float x = acc + dt_bias[h];
        const float d = (x > 20.f) ? x : log1pf(expf(x));
        dArr[lane * 64 + h] = d;
        aArr[lane * 64 + h] = expf(-d * expf(A_log[h]));
    }
}

// ---------------- k_feats: collapsed SSM -> feats in k-panel layout ---------------
__global__ __launch_bounds__(256) void k_feats(const float* __restrict__ u,
                                               const float* __restrict__ aArr,
                                               const float* __restrict__ dArr,
                                               float* __restrict__ feats_p) {
    const int t = blockIdx.x >> 2;
    const int b = blockIdx.x & 3;
    const int tid = threadIdx.x;
    const int K = 16 - t;          // unroll updates k = 0..K
    const int nvec = t + 5;        // (t+1) scan vectors + 4 unroll vectors

    __shared__ float q[16][64];
    __shared__ float cu[4][64];
    __shared__ float WV[20][32];
    __shared__ float Bv[20][128];

    if (tid < 64) {
        const int h = tid;
        const int mt = t * 4 + b;
        const float a   = aArr[mt * 64 + h];
        const float dtv = dArr[mt * 64 + h];
        float p = 1.f;
        float c3 = 0.f, c2 = 0.f, c1 = 0.f, c0 = 0.f, cs = 0.f;
        for (int j = 0; j <= K + 1; ++j) {     // p = a^j at loop head
            if (j <= K - 3) c3 += p;
            if (j == K - 2) c2 = p;
            if (j == K - 1) c1 = p;
            if (j == K)     c0 = p;
            if (j == K + 1) cs = p;
            p *= a;
        }
        cu[0][h] = dtv * c0;
        cu[1][h] = dtv * c1;
        cu[2][h] = dtv * c2;
        cu[3][h] = dtv * c3;
        float prod = 1.f;
        for (int s = t; s >= 0; --s) {
            const int ms = s * 4 + b;
            q[s][h] = cs * prod * dArr[ms * 64 + h];
            prod *= aArr[ms * 64 + h];
        }
    }
    __syncthreads();

    {   // head-reduced x vectors (32 wide each)
        const int i = tid & 31;
        const int vs = tid >> 5;
        for (int v = vs; v < nvec; v += 8) {
            float acc = 0.f;
            if (v <= t) {
                const float* base = u + (size_t)(v * 4 + b) * XB_COLS;
                for (int h = 0; h < 64; ++h) acc += q[v][h] * base[h * 32 + i];
            } else {
                const int kk = v - t - 1;
                const float* base = u + ((size_t)kk * NTOK + t * 4 + b) * XB_COLS;
                for (int h = 0; h < 64; ++h) acc += cu[kk][h] * base[h * 32 + i];
            }
            WV[v][i] = acc;
        }
    }
    for (int x = tid; x < nvec * 128; x += 256) {
        const int v = x >> 7, n = x & 127;
        size_t src;
        if (v <= t) src = (size_t)(v * 4 + b) * XB_COLS + 2048 + n;
        else        src = ((size_t)(v - t - 1) * NTOK + t * 4 + b) * XB_COLS + 2048 + n;
        Bv[v][n] = u[src];
    }
    __syncthreads();

    {   // rank-nvec outer products -> feats panel [k/4][64 rows][4]
        const int i  = tid >> 3;            // headdim index 0..31
        const int n0 = (tid & 7) * 16;      // state offset
        const int r  = b * 16 + t;          // output row (matches out layout)
        float acc[16];
#pragma unroll
        for (int nn = 0; nn < 16; ++nn) acc[nn] = 0.f;
        for (int v = 0; v < nvec; ++v) {
            const float wvv = WV[v][i];
#pragma unroll
            for (int nn = 0; nn < 16; ++nn) acc[nn] += wvv * Bv[v][n0 + nn];
        }
        float4* fp4 = reinterpret_cast<float4*>(feats_p);
#pragma unroll
        for (int qq = 0; qq < 4; ++qq) {
            const int kq = i * 32 + (tid & 7) * 4 + qq;
            float4 v4;
            v4.x = acc[qq * 4 + 0] * (1.f / 64.f);
            v4.y = acc[qq * 4 + 1] * (1.f / 64.f);
            v4.z = acc[qq * 4 + 2] * (1.f / 64.f);
            v4.w = acc[qq * 4 + 3] * (1.f / 64.f);
            fp4[(size_t)kq * 64 + r] = v4;
        }
    }
}

// ---------------- k_cls: classifier GEMM, LDS-staged, token-pair x class-pair -----
// grid (40, KC) x 256 thr (4 waves). Block: 64 classes x (4096/KC)-k chunk.
// Wave: 16 classes as 8 pairs; lane (m2,h): tokens {m2,m2+32}, class-slot h.
// Per 64-k subtile: stage 16KB -> per pair 16 ds_read_b128 feeding 128 FMAs.
__global__ __launch_bounds__(256, 3) void k_cls(const float* __restrict__ feats_p,
                                                const float* __restrict__ Wc,
                                                float* __restrict__ partialD) {
    const int tid  = threadIdx.x;
    const int m2   = tid & 31;
    const int h    = (tid >> 5) & 1;
    const int wv   = tid >> 6;
    const int KC   = gridDim.y;
    const int kc   = blockIdx.y;
    const int cls0 = blockIdx.x * 64;            // 40*64 = 2560 >= 2513
    const int nsub = (FEATDIM / KC) / 64;        // 64-k subtiles per chunk

    __shared__ float Wl[64][64];

    const float4* fp4 = reinterpret_cast<const float4*>(feats_p);
    float accA[8] = {0,0,0,0,0,0,0,0}, accB[8] = {0,0,0,0,0,0,0,0};

    const int r0 = tid >> 4, ks = tid & 15;      // staging map

    for (int st = 0; st < nsub; ++st) {
        const int kbase = (kc * nsub + st) * 64;
        __syncthreads();                         // protect Wl reuse
#pragma unroll
        for (int j = 0; j < 4; ++j) {
            const int row = r0 + j * 16;
            int grow = cls0 + row; if (grow > NCLASS - 1) grow = NCLASS - 1;
            *reinterpret_cast<float4*>(&Wl[row][ks * 4]) =
                *reinterpret_cast<const float4*>(Wc + (size_t)grow * FEATDIM + kbase + ks * 4);
        }
        __syncthreads();

#pragma unroll
        for (int hs = 0; hs < 2; ++hs) {         // 32-k half-subtiles
            const int kq0 = kbase / 4 + hs * 8;
            float4 fa[8], fb[8];
#pragma unroll
            for (int q = 0; q < 8; ++q) {
                fa[q] = fp4[(size_t)(kq0 + q) * 64 + m2];
                fb[q] = fp4[(size_t)(kq0 + q) * 64 + m2 + 32];
            }
#pragma unroll
            for (int p = 0; p < 8; ++p) {
                const int wrow = (wv << 4) + (p << 1) + h;
#pragma unroll
                for (int q = 0; q < 8; ++q) {
                    const float4 wq =
                        *reinterpret_cast<const float4*>(&Wl[wrow][(hs * 8 + q) * 4]);
                    FMA4(accA[p], wq, fa[q]);
                    FMA4(accB[p], wq, fb[q]);
                }
            }
        }
    }

#pragma unroll
    for (int p = 0; p < 8; ++p) {
        const int c = cls0 + (wv << 4) + (p << 1) + h;
        if (c < NCLASS) {
            partialD[((size_t)kc * NCLASS + c) * 64 + m2]      = accA[p];
            partialD[((size_t)kc * NCLASS + c) * 64 + m2 + 32] = accB[p];
        }
    }
}

// ---------------- k_out: reduce split-K partials + bias -> out --------------------
__global__ void k_out(const float* __restrict__ partialD, const float* __restrict__ cls_b,
                      float* __restrict__ out, int KC) {
    const int r  = threadIdx.x & 63;
    const int cl = threadIdx.x >> 6;
    const int c  = blockIdx.x * 4 + cl;
    if (c >= NCLASS) return;
    float s = cls_b[c];
    for (int kc = 0; kc < KC; ++kc)
        s += partialD[((size_t)kc * NCLASS + c) * 64 + r];
    out[(size_t)r * NCLASS + c] = s;
}

// ------------------------------------------------------------------------------
extern "C" void kernel_launch(void* const* d_in, const int* in_sizes, int n_in,
                              void* d_out, int out_size, void* d_ws, size_t ws_size,
                              hipStream_t stream) {
    const float* inputs  = (const float*)d_in[0];
    const float* in_proj = (const float*)d_in[1];
    const float* conv_w  = (const float*)d_in[2];
    const float* conv_b  = (const float*)d_in[3];
    const float* dt_bias = (const float*)d_in[4];
    const float* A_log   = (const float*)d_in[5];
    const float* cls_w   = (const float*)d_in[6];
    const float* cls_b   = (const float*)d_in[7];
    float* out = (float*)d_out;

    float* ws = (float*)d_ws;
    float* aArr    = ws;               //   4096
    float* dArr    = ws + 4096;        //   4096
    float* Xtp     = ws + 8192;        //  32768
    float* feats_p = ws + 40960;       // 262144
    float* scr     = ws + 303104;
    float* u       = scr;              // 557056 (dead after k_feats)
    float* partF   = scr + 557056;     // 8*2240*64 = 1146880 (dead after k_fepi)
    float* partialD = scr;             // KC*2513*64 (written after k_feats)

    // tiers: bytes = (303104 + max(1703936, KC*160832)) * 4
    //   KC=16 -> 11,505,664 (proven fitting in rounds 3/4)   KC=8 -> 8,028,160
    int KC;
    if (ws_size >= 11505664u) KC = 16;
    else                      KC = 8;

    k_xt    <<<32, 256, 0, stream>>>(inputs, Xtp);
    k_fpart <<<dim3(35, 8), 256, 0, stream>>>(Xtp, in_proj, partF);
    k_fepi  <<<560, 256, 0, stream>>>(partF, 8, conv_w, conv_b, dt_bias, A_log,
                                      u, aArr, dArr);
    k_feats <<<64, 256, 0, stream>>>(u, aArr, dArr, feats_p);
    k_cls   <<<dim3(40, KC), 256, 0, stream>>>(feats_p, cls_w, partialD);
    k_out   <<<629, 256, 0, stream>>>(partialD, cls_b, out, KC);
}

// Round 11
// 68.071 us; speedup vs baseline: 3.3290x; 3.3290x over previous
//
#include <hip/hip_runtime.h>
#include <math.h>

#define S_LEN    16
#define NTOK     64     // tokens, m = s*4 + b
#define DMODEL   512
#define XB_COLS  2176   // x part (2048) + B part (128); z and C parts are dead code
#define ZX_COLS  2240   // XB_COLS + 64 dt columns
#define NCLASS   2513
#define FEATDIM  4096
#define PD_STRIDE 2516  // padded class stride (mult of 4 -> float4-aligned rows)

typedef float f4v __attribute__((ext_vector_type(4)));

// ---------------- k_fpart: in_proj partials, standard GEMM tile ------------------
// grid (35, 8) x 256 thr. Block: 64 cols x 64 tokens x 64-k chunk.
// A/B staged [k][x]-transposed; micro-tile 4x4 per thread: per k, 2 lane-distinct
// ds_read_b128 feed 16 FMAs. Small static arrays only (no spill).
__global__ __launch_bounds__(256) void k_fpart(const float* __restrict__ X,
                                               const float* __restrict__ W,
                                               float* __restrict__ partF) {
    const int tid = threadIdx.x;
    const int kf  = blockIdx.y;               // 64-k chunk
    const int jb  = blockIdx.x * 64;          // 2240 = 35*64 exact
    const int k0  = kf * 64;

    __shared__ float A[64][64];               // [k][token]
    __shared__ float B[64][64];               // [k][col]

    {
        const int t  = tid >> 2;              // 0..63 (token / col slot)
        const int kq = tid & 3;
        const int xrow = (t & 3) * 16 + (t >> 2);   // inputs row for token t
        const int e = (jb + t < XB_COLS) ? (2048 + jb + t) : (2176 + jb + t);
#pragma unroll
        for (int q = 0; q < 4; ++q) {
            const int kk = kq * 16 + q * 4;
            const float4 va = *reinterpret_cast<const float4*>(
                X + (size_t)xrow * DMODEL + k0 + kk);
            A[kk + 0][t] = va.x; A[kk + 1][t] = va.y;
            A[kk + 2][t] = va.z; A[kk + 3][t] = va.w;
            const float4 vb = *reinterpret_cast<const float4*>(
                W + (size_t)e * DMODEL + k0 + kk);
            B[kk + 0][t] = vb.x; B[kk + 1][t] = vb.y;
            B[kk + 2][t] = vb.z; B[kk + 3][t] = vb.w;
        }
    }
    __syncthreads();

    const int ti = tid >> 4;     // token quad 0..15
    const int ci = tid & 15;     // col quad 0..15
    float acc[4][4] = {{0.f}};
#pragma unroll 4
    for (int k = 0; k < 64; ++k) {
        const f4v a = *reinterpret_cast<const f4v*>(&A[k][ti * 4]);
        const f4v b = *reinterpret_cast<const f4v*>(&B[k][ci * 4]);
#pragma unroll
        for (int j = 0; j < 4; ++j)
#pragma unroll
            for (int l = 0; l < 4; ++l)
                acc[j][l] += a[j] * b[l];
    }
#pragma unroll
    for (int l = 0; l < 4; ++l) {
        f4v s; s[0] = acc[0][l]; s[1] = acc[1][l]; s[2] = acc[2][l]; s[3] = acc[3][l];
        *reinterpret_cast<f4v*>(
            partF + ((size_t)kf * ZX_COLS + jb + ci * 4 + l) * 64 + ti * 4) = s;
    }
}

// ---------------- k_fepi: reduce partials + conv/silu + dt/dA ---------------------
__global__ __launch_bounds__(256) void k_fepi(const float* __restrict__ partF, int KF,
                                              const float* __restrict__ conv_w,
                                              const float* __restrict__ conv_b,
                                              const float* __restrict__ dt_bias,
                                              const float* __restrict__ A_log,
                                              float* __restrict__ u,
                                              float* __restrict__ aArr,
                                              float* __restrict__ dArr) {
    const int lane = threadIdx.x & 63;                 // token m
    const int j    = blockIdx.x * 4 + (threadIdx.x >> 6);
    float acc = 0.f;
    for (int kf = 0; kf < KF; ++kf)
        acc += partF[((size_t)kf * ZX_COLS + j) * 64 + lane];

    if (j < XB_COLS) {
        const float4 cwv = *reinterpret_cast<const float4*>(conv_w + j * 4);
        const float cb = conv_b[j];
        float wk[4];
        wk[0] = cwv.w;                  // cw[:,0] = conv_w[:,3]
        wk[1] = wk[0] + cwv.z;
        wk[2] = wk[1] + cwv.y;
        wk[3] = wk[2] + cwv.x;
#pragma unroll
        for (int k = 0; k < 4; ++k) {
            const float v = acc * wk[k] + cb;
            u[((size_t)k * NTOK + lane) * XB_COLS + j] = v / (1.f + expf(-v));
        }
    } else {
        const int h = j - XB_COLS;
        const float x = acc + dt_bias[h];
        const float d = (x > 20.f) ? x : log1pf(expf(x));
        dArr[lane * 64 + h] = d;
        aArr[lane * 64 + h] = expf(-d * expf(A_log[h]));
    }
}

// ---------------- k_feats: collapsed SSM -> feats ROW-major [r][4096] -------------
__global__ __launch_bounds__(256) void k_feats(const float* __restrict__ u,
                                               const float* __restrict__ aArr,
                                               const float* __restrict__ dArr,
                                               float* __restrict__ feats) {
    const int t = blockIdx.x >> 2;
    const int b = blockIdx.x & 3;
    const int tid = threadIdx.x;
    const int K = 16 - t;          // unroll updates k = 0..K
    const int nvec = t + 5;        // (t+1) scan vectors + 4 unroll vectors

    __shared__ float q[16][64];
    __shared__ float cu[4][64];
    __shared__ float WV[20][32];
    __shared__ float Bv[20][128];

    if (tid < 64) {
        const int h = tid;
        const int mt = t * 4 + b;
        const float a   = aArr[mt * 64 + h];
        const float dtv = dArr[mt * 64 + h];
        float p = 1.f;
        float c3 = 0.f, c2 = 0.f, c1 = 0.f, c0 = 0.f, cs = 0.f;
        for (int j = 0; j <= K + 1; ++j) {     // p = a^j at loop head
            if (j <= K - 3) c3 += p;
            if (j == K - 2) c2 = p;
            if (j == K - 1) c1 = p;
            if (j == K)     c0 = p;
            if (j == K + 1) cs = p;
            p *= a;
        }
        cu[0][h] = dtv * c0;
        cu[1][h] = dtv * c1;
        cu[2][h] = dtv * c2;
        cu[3][h] = dtv * c3;
        float prod = 1.f;
        for (int s = t; s >= 0; --s) {
            const int ms = s * 4 + b;
            q[s][h] = cs * prod * dArr[ms * 64 + h];
            prod *= aArr[ms * 64 + h];
        }
    }
    __syncthreads();

    {   // head-reduced x vectors (32 wide each)
        const int i = tid & 31;
        const int vs = tid >> 5;
        for (int v = vs; v < nvec; v += 8) {
            float acc = 0.f;
            if (v <= t) {
                const float* base = u + (size_t)(v * 4 + b) * XB_COLS;
                for (int h = 0; h < 64; ++h) acc += q[v][h] * base[h * 32 + i];
            } else {
                const int kk = v - t - 1;
                const float* base = u + ((size_t)kk * NTOK + t * 4 + b) * XB_COLS;
                for (int h = 0; h < 64; ++h) acc += cu[kk][h] * base[h * 32 + i];
            }
            WV[v][i] = acc;
        }
    }
    for (int x = tid; x < nvec * 128; x += 256) {
        const int v = x >> 7, n = x & 127;
        size_t src;
        if (v <= t) src = (size_t)(v * 4 + b) * XB_COLS + 2048 + n;
        else        src = ((size_t)(v - t - 1) * NTOK + t * 4 + b) * XB_COLS + 2048 + n;
        Bv[v][n] = u[src];
    }
    __syncthreads();

    {   // rank-nvec outer products -> feats[r][4096] row-major
        const int i  = tid >> 3;            // headdim index 0..31
        const int n0 = (tid & 7) * 16;      // state offset
        const int r  = b * 16 + t;          // output row
        float acc[16];
#pragma unroll
        for (int nn = 0; nn < 16; ++nn) acc[nn] = 0.f;
        for (int v = 0; v < nvec; ++v) {
            const float wvv = WV[v][i];
#pragma unroll
            for (int nn = 0; nn < 16; ++nn) acc[nn] += wvv * Bv[v][n0 + nn];
        }
        float* dst = feats + (size_t)r * FEATDIM + i * 128 + n0;
#pragma unroll
        for (int qq = 0; qq < 4; ++qq) {
            float4 v4;
            v4.x = acc[qq * 4 + 0] * (1.f / 64.f);
            v4.y = acc[qq * 4 + 1] * (1.f / 64.f);
            v4.z = acc[qq * 4 + 2] * (1.f / 64.f);
            v4.w = acc[qq * 4 + 3] * (1.f / 64.f);
            *reinterpret_cast<float4*>(dst + qq * 4) = v4;
        }
    }
}

// ---------------- k_cls: classifier GEMM, standard tile, micro 4x8 ---------------
// grid (20, KC) x 256 thr. Block: 128 classes x 64 tokens x (4096/KC)-k chunk.
// Per 64-k subtile: stage A[64k][64t] (16KB) + B[64k][128c] (32KB) transposed;
// per k: 3 lane-distinct ds_read_b128 feed 32 FMAs (acc[4][8], static).
__global__ __launch_bounds__(256) void k_cls(const float* __restrict__ feats,
                                             const float* __restrict__ Wc,
                                             float* __restrict__ partialD) {
    const int tid   = threadIdx.x;
    const int ks    = blockIdx.y;
    const int cbase = blockIdx.x * 128;          // 20*128 = 2560 >= 2513
    const int chunk = FEATDIM / gridDim.y;
    const int nsub  = chunk / 64;

    __shared__ float A[64][64];                  // [k][token]
    __shared__ float B[64][128];                 // [k][class]

    const int ti = tid >> 4;                     // token quad 0..15
    const int ci = tid & 15;                     // class octet 0..15
    float acc[4][8] = {{0.f}};

    for (int st = 0; st < nsub; ++st) {
        const int k0 = ks * chunk + st * 64;
        __syncthreads();                         // protect A/B reuse
        {
            const int t = tid >> 2, kq = tid & 3;
#pragma unroll
            for (int q = 0; q < 4; ++q) {
                const int kk = kq * 16 + q * 4;
                const float4 v = *reinterpret_cast<const float4*>(
                    feats + (size_t)t * FEATDIM + k0 + kk);
                A[kk + 0][t] = v.x; A[kk + 1][t] = v.y;
                A[kk + 2][t] = v.z; A[kk + 3][t] = v.w;
            }
#pragma unroll
            for (int h = 0; h < 2; ++h) {
                const int c = (tid >> 2) + h * 64;
                int cr = cbase + c; if (cr > NCLASS - 1) cr = NCLASS - 1;
#pragma unroll
                for (int q = 0; q < 4; ++q) {
                    const int kk = kq * 16 + q * 4;
                    const float4 v = *reinterpret_cast<const float4*>(
                        Wc + (size_t)cr * FEATDIM + k0 + kk);
                    B[kk + 0][c] = v.x; B[kk + 1][c] = v.y;
                    B[kk + 2][c] = v.z; B[kk + 3][c] = v.w;
                }
            }
        }
        __syncthreads();

#pragma unroll 2
        for (int k = 0; k < 64; ++k) {
            const f4v a  = *reinterpret_cast<const f4v*>(&A[k][ti * 4]);
            const f4v b0 = *reinterpret_cast<const f4v*>(&B[k][ci * 8]);
            const f4v b1 = *reinterpret_cast<const f4v*>(&B[k][ci * 8 + 4]);
#pragma unroll
            for (int j = 0; j < 4; ++j) {
#pragma unroll
                for (int l = 0; l < 4; ++l) {
                    acc[j][l]     += a[j] * b0[l];
                    acc[j][l + 4] += a[j] * b1[l];
                }
            }
        }
    }

    const size_t obase = (size_t)ks * (NTOK * PD_STRIDE);
    if (cbase + 127 < NCLASS) {                  // full blocks: vector stores
#pragma unroll
        for (int j = 0; j < 4; ++j) {
            f4v s0, s1;
#pragma unroll
            for (int l = 0; l < 4; ++l) { s0[l] = acc[j][l]; s1[l] = acc[j][l + 4]; }
            float* dst = partialD + obase + (size_t)(ti * 4 + j) * PD_STRIDE
                       + cbase + ci * 8;
            *reinterpret_cast<f4v*>(dst)     = s0;
            *reinterpret_cast<f4v*>(dst + 4) = s1;
        }
    } else {                                     // tail block: guarded scalar
#pragma unroll
        for (int j = 0; j < 4; ++j)
#pragma unroll
            for (int l = 0; l < 8; ++l) {
                const int c = cbase + ci * 8 + l;
                if (c < NCLASS)
                    partialD[obase + (size_t)(ti * 4 + j) * PD_STRIDE + c] = acc[j][l];
            }
    }
}

// ---------------- k_out: reduce split-K partials + bias -> out --------------------
__global__ void k_out(const float* __restrict__ partialD, const float* __restrict__ cls_b,
                      float* __restrict__ out, int KC) {
    const int bx = blockIdx.x;                   // 640 = 64 rows * 10 c-chunks
    const int r  = bx / 10;
    const int c  = (bx % 10) * 256 + threadIdx.x;
    if (c >= NCLASS) return;
    float s = cls_b[c];
    for (int ks = 0; ks < KC; ++ks)
        s += partialD[(size_t)ks * (NTOK * PD_STRIDE) + (size_t)r * PD_STRIDE + c];
    out[(size_t)r * NCLASS + c] = s;
}

// ------------------------------------------------------------------------------
extern "C" void kernel_launch(void* const* d_in, const int* in_sizes, int n_in,
                              void* d_out, int out_size, void* d_ws, size_t ws_size,
                              hipStream_t stream) {
    const float* inputs  = (const float*)d_in[0];
    const float* in_proj = (const float*)d_in[1];
    const float* conv_w  = (const float*)d_in[2];
    const float* conv_b  = (const float*)d_in[3];
    const float* dt_bias = (const float*)d_in[4];
    const float* A_log   = (const float*)d_in[5];
    const float* cls_w   = (const float*)d_in[6];
    const float* cls_b   = (const float*)d_in[7];
    float* out = (float*)d_out;

    float* ws = (float*)d_ws;
    float* aArr    = ws;               //   4096
    float* dArr    = ws + 4096;        //   4096
    float* feats   = ws + 8192;        // 262144 (row-major [r][4096])
    float* scr     = ws + 270336;
    float* u       = scr;              // 557056 (dead after k_feats)
    float* partF   = scr + 557056;     // 8*2240*64 = 1146880 (dead after k_fepi)
    float* partialD = scr;             // KC*64*2516 (written after k_feats)

    // tiers: bytes = (270336 + max(1703936, KC*64*2516)) * 4
    //   KC=16 -> 11,386,880 (< 11,505,664 proven in round 3)
    //   KC=8  ->  7,897,088 (proven tier)
    int KC;
    if (ws_size >= 11386880u) KC = 16;
    else                      KC = 8;

    k_fpart <<<dim3(35, 8), 256, 0, stream>>>(inputs, in_proj, partF);
    k_fepi  <<<560, 256, 0, stream>>>(partF, 8, conv_w, conv_b, dt_bias, A_log,
                                      u, aArr, dArr);
    k_feats <<<64, 256, 0, stream>>>(u, aArr, dArr, feats);
    k_cls   <<<dim3(20, KC), 256, 0, stream>>>(feats, cls_w, partialD);
    k_out   <<<640, 256, 0, stream>>>(partialD, cls_b, out, KC);
}